// Round 2
// 399.920 us; speedup vs baseline: 1.2411x; 1.2411x over previous
//
#include <hip/hip_runtime.h>

// Problem constants (from reference setup_inputs / NUM_DISPARITIES)
constexpr int B = 2, C = 32, H = 136, W = 240, D = 48;
constexpr int W4     = W / 4;          // 60 float4 per row
constexpr int PLANE  = H * W;          // 32640 elements per (b,c,d) plane
constexpr int ROWS   = 4;              // rows per block (one per wave)
constexpr int HCHUNK = H / ROWS;       // 34 row-chunks
constexpr int NBLK   = B * C * HCHUNK; // 2176 blocks
constexpr float CLAMPV = 1000.0f;

// LDS row layout (floats): [0..63] zero pad (implements w<d masking for free),
// [64..303] the 240 floats of one right row, [304..311] slack. 312*4B = 1248 B,
// 16B-aligned so every windowed read below is a ds_read_b128.
constexpr int LROW = 312;

typedef float v4f __attribute__((ext_vector_type(4)));

__device__ __forceinline__ float clampv(float x) {
    return fminf(CLAMPV, fmaxf(-CLAMPV, x));  // -> v_med3_f32
}

// Block = (bc, 4-row chunk). Wave g owns row h0+g: stages the right row into
// its private LDS row ONCE (zero-padded left edge), keeps left float4 in regs,
// then produces all 48 disparity outputs for its 60 float4 columns.
// For 4 consecutive disparities d = 4q..4q+3, the 4 sliding windows
// right[4*lane-d .. +3] are covered by two adjacent 16B LDS reads X,Y:
//   d=4q   : [Y0 Y1 Y2 Y3]
//   d=4q+1 : [X3 Y0 Y1 Y2]
//   d=4q+2 : [X2 X3 Y0 Y1]
//   d=4q+3 : [X1 X2 X3 Y0]
// so the gather costs 2 DS reads per 4 output rows — no compares, no masks,
// no division, no barrier (each wave touches only its own LDS row).
__global__ __launch_bounds__(256) void CostVolume_4939212390829_kernel(
        const float* __restrict__ left,
        const float* __restrict__ right,
        float* __restrict__ out) {
    const int blk  = blockIdx.x;
    const int bc   = blk / HCHUNK;
    const int h0   = (blk - bc * HCHUNK) * ROWS;
    const int g    = threadIdx.x >> 6;    // wave id = row within chunk
    const int lane = threadIdx.x & 63;
    const int h    = h0 + g;

    __shared__ v4f lds_v[ROWS * (LROW / 4)];   // v4f-typed -> 16B aligned
    float* lrow = reinterpret_cast<float*>(lds_v) + g * LROW;

    const size_t inoff = (size_t)bc * PLANE + (size_t)h * W;

    // zero the 64-float left pad (lanes 0..15, 16B each)
    if (lane < 16) {
        v4f z = {0.0f, 0.0f, 0.0f, 0.0f};
        *reinterpret_cast<v4f*>(lrow + 4 * lane) = z;
    }

    v4f l4 = {0.0f, 0.0f, 0.0f, 0.0f};
    if (lane < W4) {
        // stage right row into LDS floats [64..303]; left stays in registers
        *reinterpret_cast<v4f*>(lrow + 64 + 4 * lane) =
            *reinterpret_cast<const v4f*>(right + inoff + 4 * lane);
        l4 = *reinterpret_cast<const v4f*>(left + inoff + 4 * lane);
    }

    if (lane >= W4) return;   // no barrier anywhere: LDS rows are wave-private

    // X window base for q=0: row float 60 + 4*lane  (= data index 4*lane - 4)
    const float* px0 = lrow + 60 + 4 * lane;
    // output element index for d=0 at this (h, w): fits u32 (max ~100M)
    const uint32_t obase = (uint32_t)(bc * D) * PLANE + (uint32_t)h * W + 4 * lane;

    for (int q = 0; q < D / 4; ++q) {
        const float* px = px0 - 4 * q;
        const v4f X = *reinterpret_cast<const v4f*>(px);       // data[4l-4q-4 ..]
        const v4f Y = *reinterpret_cast<const v4f*>(px + 4);   // data[4l-4q   ..]
        const uint32_t o0 = obase + (uint32_t)(4 * q) * PLANE;

        v4f o;
        // d = 4q
        o.x = clampv(l4.x * Y.x); o.y = clampv(l4.y * Y.y);
        o.z = clampv(l4.z * Y.z); o.w = clampv(l4.w * Y.w);
        __builtin_nontemporal_store(o, reinterpret_cast<v4f*>(out + o0));
        // d = 4q+1
        o.x = clampv(l4.x * X.w); o.y = clampv(l4.y * Y.x);
        o.z = clampv(l4.z * Y.y); o.w = clampv(l4.w * Y.z);
        __builtin_nontemporal_store(o, reinterpret_cast<v4f*>(out + o0 + PLANE));
        // d = 4q+2
        o.x = clampv(l4.x * X.z); o.y = clampv(l4.y * X.w);
        o.z = clampv(l4.z * Y.x); o.w = clampv(l4.w * Y.y);
        __builtin_nontemporal_store(o, reinterpret_cast<v4f*>(out + o0 + 2 * PLANE));
        // d = 4q+3
        o.x = clampv(l4.x * X.y); o.y = clampv(l4.y * X.z);
        o.z = clampv(l4.z * X.w); o.w = clampv(l4.w * Y.x);
        __builtin_nontemporal_store(o, reinterpret_cast<v4f*>(out + o0 + 3 * PLANE));
    }
}

extern "C" void kernel_launch(void* const* d_in, const int* in_sizes, int n_in,
                              void* d_out, int out_size, void* d_ws, size_t ws_size,
                              hipStream_t stream) {
    const float* left  = (const float*)d_in[0];
    const float* right = (const float*)d_in[1];
    float* out = (float*)d_out;
    (void)in_sizes; (void)n_in; (void)out_size; (void)d_ws; (void)ws_size;

    CostVolume_4939212390829_kernel<<<NBLK, 256, 0, stream>>>(left, right, out);
}